// Round 6
// baseline (7583.533 us; speedup 1.0000x reference)
//
#include <hip/hip_runtime.h>
#include <math.h>

#define NHID   1024
#define NSTEP  512
#define NB     32
#define NSPLIT 8          // blocks per batch (column split)
#define COLS   128        // NHID / NSPLIT = block size
#define NWORDS 16         // 1024-bit spike mask as u64 words

// 256 blocks = 32 batches x 8 column-splits, 128 threads each.
// blk = j*32 + b  ->  all 8 splits of batch b land on XCD b%8 (round-robin
// heuristic; correctness does not depend on it). Per step: publish 2 ballot
// words + seq (release), poll 8 seq words (acquire), gather h2h rows for this
// block's 128 columns in ascending-row order (bitwise round-1 numerics).
// No threadfence, no atomic RMW in the hot path.
__global__ __launch_bounds__(COLS, 1)
void coesn_kernel(const float* __restrict__ x,
                  const float* __restrict__ x2h,
                  const float* __restrict__ h2h,
                  const float* __restrict__ bias,
                  const float* __restrict__ gamma_,
                  const float* __restrict__ eps_,
                  float* __restrict__ out,
                  unsigned long long* __restrict__ masks,  // [2][NB][NWORDS]
                  unsigned int* __restrict__ seq,          // [NB][32] (128B/batch)
                  float ref_decay)
{
#pragma clang fp contract(off)
    const int tid  = threadIdx.x;
    const int blk  = blockIdx.x;
    const int b    = blk & 31;      // batch
    const int j    = blk >> 5;      // column split
    const int col  = j * COLS + tid;
    const int w    = tid >> 6;      // wave in block (0..1)
    const int lane = tid & 63;

    __shared__ float xs[NSTEP];
    __shared__ int   idx[NHID];
    __shared__ unsigned long long mw[NWORDS];
    __shared__ int cnts[NWORDS];

    for (int i = tid; i < NSTEP; i += COLS) xs[i] = x[b * NSTEP + i];

    const float w_in = x2h[col];
    const float bi   = bias[col];
    const float ga   = gamma_[col];
    const float ep   = eps_[col];

    float hy = 0.0f, hz = 0.0f, ref = 0.0f, lv = 0.0f;
    int scount = 0;
    int p = 0;                       // mask parity currently being READ

    __syncthreads();

    for (int t = 0; t < NSTEP; ++t) {
        // ---- read step-(t-1) spike mask (zeros at t=0, from memset) ----
        if (tid < NWORDS) {
            unsigned long long v = __hip_atomic_load(
                &masks[(p * NB + b) * NWORDS + tid],
                __ATOMIC_RELAXED, __HIP_MEMORY_SCOPE_AGENT);
            mw[tid] = v;
            cnts[tid] = __popcll(v);
        }
        __syncthreads();

        // ---- expand mask -> ascending index list ----
        int total = 0;
        #pragma unroll
        for (int i = 0; i < NWORDS; ++i) total += cnts[i];
        if (tid < NWORDS) {
            int off = 0;
            for (int i = 0; i < tid; ++i) off += cnts[i];
            unsigned long long wv = mw[tid];
            int base = tid << 6;
            while (wv) {
                int bit = __builtin_ctzll(wv);
                idx[off++] = base + bit;
                wv &= wv - 1ull;
            }
        }
        __syncthreads();

        // ---- gather: ascending rows, single ordered accumulator chain ----
        float acc = 0.0f;
        int k = 0;
        for (; k + 16 <= total; k += 16) {
            int4 i0 = *(const int4*)&idx[k];       // LDS broadcast reads
            int4 i1 = *(const int4*)&idx[k + 4];
            int4 i2 = *(const int4*)&idx[k + 8];
            int4 i3 = *(const int4*)&idx[k + 12];
            int r0  = __builtin_amdgcn_readfirstlane(i0.x);
            int r1  = __builtin_amdgcn_readfirstlane(i0.y);
            int r2  = __builtin_amdgcn_readfirstlane(i0.z);
            int r3  = __builtin_amdgcn_readfirstlane(i0.w);
            int r4  = __builtin_amdgcn_readfirstlane(i1.x);
            int r5  = __builtin_amdgcn_readfirstlane(i1.y);
            int r6  = __builtin_amdgcn_readfirstlane(i1.z);
            int r7  = __builtin_amdgcn_readfirstlane(i1.w);
            int r8  = __builtin_amdgcn_readfirstlane(i2.x);
            int r9  = __builtin_amdgcn_readfirstlane(i2.y);
            int r10 = __builtin_amdgcn_readfirstlane(i2.z);
            int r11 = __builtin_amdgcn_readfirstlane(i2.w);
            int r12 = __builtin_amdgcn_readfirstlane(i3.x);
            int r13 = __builtin_amdgcn_readfirstlane(i3.y);
            int r14 = __builtin_amdgcn_readfirstlane(i3.z);
            int r15 = __builtin_amdgcn_readfirstlane(i3.w);
            float v0  = h2h[((size_t)r0  << 10) + col];
            float v1  = h2h[((size_t)r1  << 10) + col];
            float v2  = h2h[((size_t)r2  << 10) + col];
            float v3  = h2h[((size_t)r3  << 10) + col];
            float v4  = h2h[((size_t)r4  << 10) + col];
            float v5  = h2h[((size_t)r5  << 10) + col];
            float v6  = h2h[((size_t)r6  << 10) + col];
            float v7  = h2h[((size_t)r7  << 10) + col];
            float v8  = h2h[((size_t)r8  << 10) + col];
            float v9  = h2h[((size_t)r9  << 10) + col];
            float v10 = h2h[((size_t)r10 << 10) + col];
            float v11 = h2h[((size_t)r11 << 10) + col];
            float v12 = h2h[((size_t)r12 << 10) + col];
            float v13 = h2h[((size_t)r13 << 10) + col];
            float v14 = h2h[((size_t)r14 << 10) + col];
            float v15 = h2h[((size_t)r15 << 10) + col];
            acc += v0;  acc += v1;  acc += v2;  acc += v3;
            acc += v4;  acc += v5;  acc += v6;  acc += v7;
            acc += v8;  acc += v9;  acc += v10; acc += v11;
            acc += v12; acc += v13; acc += v14; acc += v15;
        }
        for (; k < total; ++k) {
            int r = __builtin_amdgcn_readfirstlane(idx[k]);
            acc += h2h[((size_t)r << 10) + col];
        }

        // ---- LIF (exact reference expression order, no FMA) ----
        float xv  = xs[t];
        float pp  = xv * w_in;
        float q   = pp + acc;
        float cur = q + bi;

        float aa = (-lv) / 20.0f;
        float bb = aa + cur;
        lv = lv + 0.042f * bb;
        float ls = (lv > 0.05f) ? 1.0f : 0.0f;
        lv = lv - ls * 0.05f;

        // ---- HRF oscillator ----
        float t1 = 35.0f * ls;
        float t2 = ga * hy;
        float t3 = ep * hz;
        float t4 = (t1 - t2) - t3;
        hz = hz + 0.042f * t4;
        hy = hy + 0.042f * hz;

        float sv = (hy - 0.05f) - ref;
        int sp = (sv > 0.0f) ? 1 : 0;
        ref = ref * ref_decay + (sp ? 1.0f : 0.0f);
        scount += sp;

        // ---- publish + seq barrier (skip after last step) ----
        unsigned long long bal = __ballot(sp);
        if (t < NSTEP - 1) {
            int pn = p ^ 1;
            if (lane == 0) {
                __hip_atomic_store(&masks[(pn * NB + b) * NWORDS + (j * 2 + w)],
                                   bal, __ATOMIC_RELEASE,
                                   __HIP_MEMORY_SCOPE_AGENT);
            }
            __syncthreads();   // both waves' mask stores retired (vmcnt drain)
            if (tid == 0) {
                __hip_atomic_store(&seq[b * 32 + j], (unsigned)(t + 1),
                                   __ATOMIC_RELEASE, __HIP_MEMORY_SCOPE_AGENT);
            }
            if (tid < NSPLIT) {
                while (__hip_atomic_load(&seq[b * 32 + tid], __ATOMIC_ACQUIRE,
                                         __HIP_MEMORY_SCOPE_AGENT)
                       < (unsigned)(t + 1))
                    __builtin_amdgcn_s_sleep(1);
            }
            p = pn;
            __syncthreads();   // all 8 seq seen -> masks[pn] readable
        }
    }

    out[b * NHID + col] = (float)scount * (1.0f / 512.0f);
}

extern "C" void kernel_launch(void* const* d_in, const int* in_sizes, int n_in,
                              void* d_out, int out_size, void* d_ws, size_t ws_size,
                              hipStream_t stream) {
    const float* x     = (const float*)d_in[0];
    const float* x2h   = (const float*)d_in[1];
    const float* h2h   = (const float*)d_in[2];
    const float* bias  = (const float*)d_in[3];
    const float* gamma = (const float*)d_in[4];
    const float* eps   = (const float*)d_in[5];
    float* out = (float*)d_out;

    // ws: [0,4096) u32 seq[NB][32]; [4096,12288) u64 masks[2][NB][NWORDS]
    unsigned int* seq = (unsigned int*)d_ws;
    unsigned long long* masks = (unsigned long long*)((char*)d_ws + 4096);

    hipMemsetAsync(d_ws, 0, 16384, stream);   // zero seq + both mask buffers

    float ref_decay = (float)exp(-(0.042 / 0.25));

    coesn_kernel<<<NB * NSPLIT, COLS, 0, stream>>>(
        x, x2h, h2h, bias, gamma, eps, out, masks, seq, ref_decay);
}

// Round 7
// 3663.737 us; speedup vs baseline: 2.0699x; 2.0699x over previous
//
#include <hip/hip_runtime.h>
#include <math.h>

#define NHID   1024
#define NSTEP  512
#define NB     32
#define NSPLIT 8          // blocks per batch (column split)
#define COLS   128        // NHID / NSPLIT = block size
#define NWORDS 16         // 1024-bit spike mask as u64 words

// 256 blocks = 32 batches x 8 column-splits, 128 threads each.
// Hot-path sync uses ONLY relaxed agent-scope atomics (sc1 accesses, no
// buffer_inv/wbl2 cache maintenance) so the per-XCD L2 stays warm with h2h.
// Ordering: mask store -> __syncthreads (vmcnt drain) -> seq store; reader
// branches on polled seq before issuing mask loads. h2h is read-only, needs
// no fences. Gather: ascending rows, 32 loads in flight, single ordered
// accumulator chain (bitwise round-1 numerics).
__global__ __launch_bounds__(COLS, 1)
void coesn_kernel(const float* __restrict__ x,
                  const float* __restrict__ x2h,
                  const float* __restrict__ h2h,
                  const float* __restrict__ bias,
                  const float* __restrict__ gamma_,
                  const float* __restrict__ eps_,
                  float* __restrict__ out,
                  unsigned long long* __restrict__ masks,  // [2][NB][NWORDS]
                  unsigned int* __restrict__ seq,          // [NB][32]
                  float ref_decay)
{
#pragma clang fp contract(off)
    const int tid  = threadIdx.x;
    const int blk  = blockIdx.x;
    const int b    = blk & 31;      // batch
    const int j    = blk >> 5;      // column split
    const int col  = j * COLS + tid;
    const int w    = tid >> 6;      // wave in block (0..1)
    const int lane = tid & 63;

    __shared__ float xs[NSTEP];
    __shared__ int   idx[NHID];
    __shared__ unsigned long long mw[NWORDS];
    __shared__ int cnts[NWORDS];

    for (int i = tid; i < NSTEP; i += COLS) xs[i] = x[b * NSTEP + i];

    const float w_in = x2h[col];
    const float bi   = bias[col];
    const float ga   = gamma_[col];
    const float ep   = eps_[col];

    float hy = 0.0f, hz = 0.0f, ref = 0.0f, lv = 0.0f;
    int scount = 0;
    int p = 0;                       // mask parity currently being READ

    __syncthreads();

    for (int t = 0; t < NSTEP; ++t) {
        // ---- read step-(t-1) spike mask (relaxed agent: sc1, no inv) ----
        if (tid < NWORDS) {
            unsigned long long v = __hip_atomic_load(
                &masks[(p * NB + b) * NWORDS + tid],
                __ATOMIC_RELAXED, __HIP_MEMORY_SCOPE_AGENT);
            mw[tid] = v;
            cnts[tid] = __popcll(v);
        }
        __syncthreads();

        // ---- expand mask -> ascending index list ----
        int total = 0;
        #pragma unroll
        for (int i = 0; i < NWORDS; ++i) total += cnts[i];
        if (tid < NWORDS) {
            int off = 0;
            for (int i = 0; i < tid; ++i) off += cnts[i];
            unsigned long long wv = mw[tid];
            int base = tid << 6;
            while (wv) {
                int bit = __builtin_ctzll(wv);
                idx[off++] = base + bit;
                wv &= wv - 1ull;
            }
        }
        __syncthreads();

        // ---- gather: ascending rows, ordered chain, 32 loads in flight ----
        float acc = 0.0f;
        int k = 0;
        for (; k + 32 <= total; k += 32) {
            int r[32];
            #pragma unroll
            for (int u = 0; u < 8; ++u) {
                int4 iv = *(const int4*)&idx[k + 4 * u];
                r[4*u+0] = __builtin_amdgcn_readfirstlane(iv.x);
                r[4*u+1] = __builtin_amdgcn_readfirstlane(iv.y);
                r[4*u+2] = __builtin_amdgcn_readfirstlane(iv.z);
                r[4*u+3] = __builtin_amdgcn_readfirstlane(iv.w);
            }
            float v[32];
            #pragma unroll
            for (int u = 0; u < 32; ++u)
                v[u] = h2h[((size_t)r[u] << 10) + col];
            #pragma unroll
            for (int u = 0; u < 32; ++u)
                acc += v[u];                       // ascending, single chain
        }
        for (; k + 8 <= total; k += 8) {
            int r[8];
            #pragma unroll
            for (int u = 0; u < 2; ++u) {
                int4 iv = *(const int4*)&idx[k + 4 * u];
                r[4*u+0] = __builtin_amdgcn_readfirstlane(iv.x);
                r[4*u+1] = __builtin_amdgcn_readfirstlane(iv.y);
                r[4*u+2] = __builtin_amdgcn_readfirstlane(iv.z);
                r[4*u+3] = __builtin_amdgcn_readfirstlane(iv.w);
            }
            float v[8];
            #pragma unroll
            for (int u = 0; u < 8; ++u)
                v[u] = h2h[((size_t)r[u] << 10) + col];
            #pragma unroll
            for (int u = 0; u < 8; ++u)
                acc += v[u];
        }
        for (; k < total; ++k) {
            int r = __builtin_amdgcn_readfirstlane(idx[k]);
            acc += h2h[((size_t)r << 10) + col];
        }

        // ---- LIF (exact reference expression order, no FMA) ----
        float xv  = xs[t];
        float pp  = xv * w_in;
        float q   = pp + acc;
        float cur = q + bi;

        float aa = (-lv) / 20.0f;
        float bb = aa + cur;
        lv = lv + 0.042f * bb;
        float ls = (lv > 0.05f) ? 1.0f : 0.0f;
        lv = lv - ls * 0.05f;

        // ---- HRF oscillator ----
        float t1 = 35.0f * ls;
        float t2 = ga * hy;
        float t3 = ep * hz;
        float t4 = (t1 - t2) - t3;
        hz = hz + 0.042f * t4;
        hy = hy + 0.042f * hz;

        float sv = (hy - 0.05f) - ref;
        int sp = (sv > 0.0f) ? 1 : 0;
        ref = ref * ref_decay + (sp ? 1.0f : 0.0f);
        scount += sp;

        // ---- publish + seq barrier (all relaxed; skip after last step) ----
        unsigned long long bal = __ballot(sp);
        if (t < NSTEP - 1) {
            int pn = p ^ 1;
            if (lane == 0) {
                __hip_atomic_store(&masks[(pn * NB + b) * NWORDS + (j * 2 + w)],
                                   bal, __ATOMIC_RELAXED,
                                   __HIP_MEMORY_SCOPE_AGENT);
            }
            __syncthreads();   // vmcnt drained: mask stores complete at L3
            if (tid == 0) {
                __hip_atomic_store(&seq[b * 32 + j], (unsigned)(t + 1),
                                   __ATOMIC_RELAXED, __HIP_MEMORY_SCOPE_AGENT);
            }
            if (tid < NSPLIT) {
                const unsigned target = (unsigned)(t + 1);
                int spin = 0;
                while (__hip_atomic_load(&seq[b * 32 + tid], __ATOMIC_RELAXED,
                                         __HIP_MEMORY_SCOPE_AGENT) < target) {
                    __builtin_amdgcn_s_sleep(1);
                    if (((++spin) & 2047) == 2047) {
                        // escape hatch: forces inv if relaxed were ever stale
                        (void)__hip_atomic_load(&seq[b * 32 + tid],
                                                __ATOMIC_ACQUIRE,
                                                __HIP_MEMORY_SCOPE_AGENT);
                    }
                }
            }
            p = pn;
            __syncthreads();   // all 8 seq observed -> masks[pn] readable
        }
    }

    out[b * NHID + col] = (float)scount * (1.0f / 512.0f);
}

extern "C" void kernel_launch(void* const* d_in, const int* in_sizes, int n_in,
                              void* d_out, int out_size, void* d_ws, size_t ws_size,
                              hipStream_t stream) {
    const float* x     = (const float*)d_in[0];
    const float* x2h   = (const float*)d_in[1];
    const float* h2h   = (const float*)d_in[2];
    const float* bias  = (const float*)d_in[3];
    const float* gamma = (const float*)d_in[4];
    const float* eps   = (const float*)d_in[5];
    float* out = (float*)d_out;

    // ws: [0,4096) u32 seq[NB][32]; [4096,12288) u64 masks[2][NB][NWORDS]
    unsigned int* seq = (unsigned int*)d_ws;
    unsigned long long* masks = (unsigned long long*)((char*)d_ws + 4096);

    hipMemsetAsync(d_ws, 0, 16384, stream);   // zero seq + both mask buffers

    float ref_decay = (float)exp(-(0.042 / 0.25));

    coesn_kernel<<<NB * NSPLIT, COLS, 0, stream>>>(
        x, x2h, h2h, bias, gamma, eps, out, masks, seq, ref_decay);
}

// Round 8
// 2339.449 us; speedup vs baseline: 3.2416x; 1.5661x over previous
//
#include <hip/hip_runtime.h>
#include <math.h>

#define NHID    1024
#define NSTEP   512
#define NB      32
#define NSPLIT  8
#define COLS    128      // columns per split
#define THREADS 512      // 8 waves
#define NWAVES  8
#define MWORDS  32       // 32-bit mask words per batch (tagged u64 each)

// 256 blocks = 32 batches x 8 column-splits, 512 threads (8 waves) each.
// Sync: each split publishes 4 tagged words  (tag<<32 | 32-bit ballot half)
// via ONE relaxed agent-scope atomic store each — no fences, no acks, no
// separate seq. Consumers poll the payload (tag==t), so flag+data arrive in
// the same load and per-XCD L2 stays warm (no acquire-invalidates).
// Gather: global ascending spike list in LDS; wave w takes positions
// k=w mod 8 with float2 loads (1 instr/row/wave), 16-deep chunks, padded
// with zero-row loads (exact +0.0f) so no shallow tail. LDS combine in
// ascending wave order. Elementwise math: exact reference order, no FMA.
__global__ __launch_bounds__(THREADS, 2)
void coesn_kernel(const float* __restrict__ x,
                  const float* __restrict__ x2h,
                  const float* __restrict__ h2h,
                  const float* __restrict__ bias,
                  const float* __restrict__ gamma_,
                  const float* __restrict__ eps_,
                  float* __restrict__ out,
                  unsigned long long* __restrict__ masks,  // [2][NB][MWORDS]
                  const float* __restrict__ zrow,          // 128 zeros
                  float ref_decay)
{
#pragma clang fp contract(off)
    const int tid  = threadIdx.x;
    const int blk  = blockIdx.x;
    const int b    = blk & 31;      // batch
    const int j    = blk >> 5;      // split (XCD = b%8 heuristic; not relied on)
    const int w    = tid >> 6;      // wave 0..7
    const int lane = tid & 63;

    __shared__ float xs[NSTEP];
    __shared__ unsigned short idxs[NHID + 128];  // padded ascending spike list
    __shared__ float part[NWAVES][COLS];
    __shared__ int   tot_sh[2];                  // total, tot_pad

    for (int i = tid; i < NSTEP; i += THREADS) xs[i] = x[b * NSTEP + i];

    float w_in = 0.f, bi = 0.f, ga = 0.f, ep = 0.f;
    if (tid < COLS) {
        int col = j * COLS + tid;
        w_in = x2h[col]; bi = bias[col]; ga = gamma_[col]; ep = eps_[col];
    }

    float hy = 0.f, hz = 0.f, ref = 0.f, lv = 0.f;
    int scount = 0;

    const int cb = j * COLS;
    const float* hrow_lane = h2h + cb + 2 * lane;   // + (r<<10) per row
    const float* zlane     = zrow + 2 * lane;

    __syncthreads();

    for (int t = 0; t < NSTEP; ++t) {
        int total = 0, tot_pad = 0;
        int inc = 0, myc = 0;
        unsigned int myw = 0;

        if (t > 0) {
            const int par = (t - 1) & 1;
            if (tid < MWORDS) {
                const unsigned long long tag = (unsigned long long)t;
                unsigned long long v;
                int spin = 0;
                for (;;) {
                    v = __hip_atomic_load(&masks[(par * NB + b) * MWORDS + tid],
                                          __ATOMIC_RELAXED,
                                          __HIP_MEMORY_SCOPE_AGENT);
                    if ((v >> 32) == tag) break;
                    __builtin_amdgcn_s_sleep(1);
                    if (((++spin) & 4095) == 4095) {  // escape hatch (cold)
                        (void)__hip_atomic_load(
                            &masks[(par * NB + b) * MWORDS + tid],
                            __ATOMIC_ACQUIRE, __HIP_MEMORY_SCOPE_AGENT);
                    }
                }
                myw = (unsigned int)v;
                myc = __popc(myw);
            }
            // inclusive scan of counts over lanes 0..31 (wave 0)
            inc = myc;
            if (w == 0) {
                #pragma unroll
                for (int d = 1; d < 32; d <<= 1) {
                    int y = __shfl_up(inc, d, 64);
                    if (lane >= d) inc += y;
                }
                if (lane == 31) {
                    tot_sh[0] = inc;
                    tot_sh[1] = (inc + 127) & ~127;
                }
            }
            __syncthreads();
            total = tot_sh[0]; tot_pad = tot_sh[1];
            if (tid < MWORDS) {
                int off = inc - myc;
                int base = tid << 5;
                unsigned int wv = myw;
                while (wv) {
                    int bit = __builtin_ctz(wv);
                    idxs[off++] = (unsigned short)(base + bit);
                    wv &= wv - 1u;
                }
            }
            for (int i = total + tid; i < tot_pad; i += THREADS)
                idxs[i] = 1024;                       // sentinel -> zero row
            __syncthreads();
        }

        // ---- gather: wave w owns positions k=w (mod 8), 16-deep chunks ----
        float ax = 0.f, ay = 0.f;
        for (int k = w; k < tot_pad; k += 128) {
            int r[16];
            #pragma unroll
            for (int u = 0; u < 16; ++u)
                r[u] = __builtin_amdgcn_readfirstlane((int)idxs[k + 8 * u]);
            const float* p[16];
            #pragma unroll
            for (int u = 0; u < 16; ++u)
                p[u] = (r[u] < 1024) ? (hrow_lane + ((size_t)r[u] << 10))
                                     : zlane;
            float2 v[16];
            #pragma unroll
            for (int u = 0; u < 16; ++u) v[u] = *(const float2*)p[u];
            #pragma unroll
            for (int u = 0; u < 16; ++u) { ax += v[u].x; ay += v[u].y; }
        }
        ((float2*)part[w])[lane] = make_float2(ax, ay);
        __syncthreads();

        if (tid < COLS) {
            float rsum = 0.f;
            #pragma unroll
            for (int ww = 0; ww < NWAVES; ++ww) rsum += part[ww][tid];

            // ---- LIF (exact reference expression order, no FMA) ----
            float xv  = xs[t];
            float pp  = xv * w_in;
            float q   = pp + rsum;
            float cur = q + bi;

            float aa = (-lv) / 20.0f;
            float bb = aa + cur;
            lv = lv + 0.042f * bb;
            float ls = (lv > 0.05f) ? 1.0f : 0.0f;
            lv = lv - ls * 0.05f;

            // ---- HRF oscillator ----
            float t1 = 35.0f * ls;
            float t2 = ga * hy;
            float t3 = ep * hz;
            float t4 = (t1 - t2) - t3;
            hz = hz + 0.042f * t4;
            hy = hy + 0.042f * hz;

            float sv = (hy - 0.05f) - ref;
            int sp = (sv > 0.0f) ? 1 : 0;
            ref = ref * ref_decay + (sp ? 1.0f : 0.0f);
            scount += sp;

            // ---- publish: 4 self-validating tagged words, relaxed agent ----
            if (t < NSTEP - 1) {
                unsigned long long bal = __ballot(sp);
                if ((tid & 31) == 0) {
                    unsigned int half = (tid & 32) ? (unsigned int)(bal >> 32)
                                                   : (unsigned int)bal;
                    unsigned long long payload =
                        (((unsigned long long)(t + 1)) << 32) | half;
                    const int par = t & 1;
                    __hip_atomic_store(
                        &masks[(par * NB + b) * MWORDS + (j * 4 + (tid >> 5))],
                        payload, __ATOMIC_RELAXED, __HIP_MEMORY_SCOPE_AGENT);
                }
            }
        }
        // next iteration's first __syncthreads orders idxs/part reuse
    }

    if (tid < COLS)
        out[b * NHID + cb + tid] = (float)scount * (1.0f / 512.0f);
}

extern "C" void kernel_launch(void* const* d_in, const int* in_sizes, int n_in,
                              void* d_out, int out_size, void* d_ws, size_t ws_size,
                              hipStream_t stream) {
    const float* x     = (const float*)d_in[0];
    const float* x2h   = (const float*)d_in[1];
    const float* h2h   = (const float*)d_in[2];
    const float* bias  = (const float*)d_in[3];
    const float* gamma = (const float*)d_in[4];
    const float* eps   = (const float*)d_in[5];
    float* out = (float*)d_out;

    // ws: [0,16384) u64 masks[2][NB][MWORDS]; [16384,16896) zero row (128 f32)
    unsigned long long* masks = (unsigned long long*)d_ws;
    const float* zrow = (const float*)((char*)d_ws + 16384);

    hipMemsetAsync(d_ws, 0, 24576, stream);   // zero masks + zero row

    float ref_decay = (float)exp(-(0.042 / 0.25));

    coesn_kernel<<<NB * NSPLIT, THREADS, 0, stream>>>(
        x, x2h, h2h, bias, gamma, eps, out, masks, zrow, ref_decay);
}

// Round 9
// 2335.512 us; speedup vs baseline: 3.2471x; 1.0017x over previous
//
#include <hip/hip_runtime.h>
#include <math.h>

#define NHID    1024
#define NSTEP   512
#define NB      32
#define NSPLIT  8
#define COLS    128
#define THREADS 512
#define NWAVES  8
#define MWORDS  32   // tagged u64 words per batch per parity (8 splits x 4)

typedef float f2 __attribute__((ext_vector_type(2)));
typedef int  v4i __attribute__((vector_size(16)));

// 256 blocks = 32 batches x 8 column-splits, 8 waves each.
// Wave w owns source split w: polls ONLY that split's 4 tagged words
// (tag<<32|ballot-half, relaxed agent atomics -> L2 stays warm), expands
// them wave-parallel (2 bits/lane, prefix popcount), then gathers that
// split's spiking rows with inline-asm buffer_load_dwordx2 (SRD over h2h,
// 16 loads in flight, vmcnt(0)+sched_barrier per chunk; sentinel rows are
// OOB -> hardware returns 0.0). Partials combined in ascending wave order
// (double-buffered -> ONE __syncthreads per step). Elementwise math in
// exact reference order, contraction off.
__global__ __launch_bounds__(THREADS, 1)
void coesn_kernel(const float* __restrict__ x,
                  const float* __restrict__ x2h,
                  const float* __restrict__ h2h,
                  const float* __restrict__ bias,
                  const float* __restrict__ gamma_,
                  const float* __restrict__ eps_,
                  float* __restrict__ out,
                  unsigned long long* __restrict__ masks,  // [2][NB][MWORDS]
                  float ref_decay)
{
#pragma clang fp contract(off)
    const int tid  = threadIdx.x;
    const int blk  = blockIdx.x;
    const int b    = blk & 31;      // batch
    const int j    = blk >> 5;      // column split
    const int w    = tid >> 6;      // wave 0..7 (= source split it serves)
    const int lane = tid & 63;

    __shared__ float xs[NSTEP];
    __shared__ unsigned short idxs[NWAVES][160];   // per-wave ascending rows
    __shared__ float part[2][NWAVES][COLS];        // double-buffered partials

    for (int i = tid; i < NSTEP; i += THREADS) xs[i] = x[b * NSTEP + i];

    float w_in = 0.f, bi = 0.f, ga = 0.f, ep = 0.f;
    if (tid < COLS) {
        int col = j * COLS + tid;
        w_in = x2h[col]; bi = bias[col]; ga = gamma_[col]; ep = eps_[col];
    }

    // SRD over h2h: base, stride=0, num_records = 4 MB (bytes), raw dword
    union { const float* p; unsigned int u[2]; } cv; cv.p = h2h;
    v4i srd = { (int)cv.u[0], (int)(cv.u[1] & 0xffffu),
                (int)(NHID * NHID * 4), 0x00020000 };

    // byte offset of this lane's column pair within a row
    const unsigned cbase = (unsigned)(j * COLS * 4 + lane * 8);

    float hy = 0.f, hz = 0.f, ref = 0.f, lv = 0.f;
    int scount = 0;

    __syncthreads();

    for (int t = 0; t < NSTEP; ++t) {
        const int par = t & 1;          // part-buffer AND publish parity
        int npad = 0;

        if (t > 0) {
            const int rpar = (t - 1) & 1;
            // ---- poll this wave's split's 4 tagged words (lanes 0-3) ----
            unsigned long long v = 0;
            if (lane < 4) {
                const unsigned long long* ap =
                    &masks[((size_t)rpar * NB + b) * MWORDS + (w << 2) + lane];
                int spin = 0;
                for (;;) {
                    v = __hip_atomic_load(ap, __ATOMIC_RELAXED,
                                          __HIP_MEMORY_SCOPE_AGENT);
                    if ((int)(v >> 32) == t) break;
                    __builtin_amdgcn_s_sleep(1);
                    if (((++spin) & 4095) == 4095)   // cold escape hatch
                        (void)__hip_atomic_load(ap, __ATOMIC_ACQUIRE,
                                                __HIP_MEMORY_SCOPE_AGENT);
                }
            }
            unsigned int hv = (unsigned int)v;
            unsigned int m0 = (unsigned)__shfl((int)hv, 0, 64);
            unsigned int m1 = (unsigned)__shfl((int)hv, 1, 64);
            unsigned int m2 = (unsigned)__shfl((int)hv, 2, 64);
            unsigned int m3 = (unsigned)__shfl((int)hv, 3, 64);
            unsigned long long lo = (unsigned long long)m0 |
                                    ((unsigned long long)m1 << 32);
            unsigned long long hi = (unsigned long long)m2 |
                                    ((unsigned long long)m3 << 32);
            int cw = __popcll(lo) + __popcll(hi);
            npad = (cw + 15) & ~15;

            // ---- wave-parallel expand: lane covers bits 2l, 2l+1 ----
            int p0 = lane << 1;
            int c0, bit0, bit1;
            if (lane < 32) {
                c0   = __popcll(lo & ((1ull << p0) - 1ull));
                bit0 = (int)((lo >> p0) & 1ull);
                bit1 = (int)((lo >> (p0 + 1)) & 1ull);
            } else {
                int q0 = p0 - 64;
                c0   = __popcll(lo) + __popcll(hi & ((1ull << q0) - 1ull));
                bit0 = (int)((hi >> q0) & 1ull);
                bit1 = (int)((hi >> (q0 + 1)) & 1ull);
            }
            int rowbase = w << 7;
            if (bit0) idxs[w][c0]        = (unsigned short)(rowbase + p0);
            if (bit1) idxs[w][c0 + bit0] = (unsigned short)(rowbase + p0 + 1);
            if (lane < npad - cw)
                idxs[w][cw + lane] = (unsigned short)1024;   // OOB sentinel
        }

        // ---- gather: 16-deep asm-pipelined chunks, ordered adds ----
        f2 ax = {0.f, 0.f};
        for (int k = 0; k < npad; k += 16) {
            const uint4* qp = (const uint4*)&idxs[w][k];
            uint4 qa = qp[0], qb = qp[1];
            unsigned rr[16];
            rr[0]=qa.x&0xffffu; rr[1]=qa.x>>16; rr[2]=qa.y&0xffffu; rr[3]=qa.y>>16;
            rr[4]=qa.z&0xffffu; rr[5]=qa.z>>16; rr[6]=qa.w&0xffffu; rr[7]=qa.w>>16;
            rr[8]=qb.x&0xffffu; rr[9]=qb.x>>16; rr[10]=qb.y&0xffffu; rr[11]=qb.y>>16;
            rr[12]=qb.z&0xffffu; rr[13]=qb.z>>16; rr[14]=qb.w&0xffffu; rr[15]=qb.w>>16;
            f2 vv[16];
            #pragma unroll
            for (int u = 0; u < 16; ++u) {
                unsigned voff = (rr[u] << 12) + cbase;
                asm volatile("buffer_load_dwordx2 %0, %1, %2, 0 offen"
                             : "=v"(vv[u]) : "v"(voff), "s"(srd));
            }
            asm volatile("s_waitcnt vmcnt(0)" ::: "memory");
            __builtin_amdgcn_sched_barrier(0);
            #pragma unroll
            for (int u = 0; u < 16; ++u) { ax.x += vv[u].x; ax.y += vv[u].y; }
        }
        *(f2*)&part[par][w][lane << 1] = ax;
        __syncthreads();                 // the ONE barrier per step

        if (tid < COLS) {
            float rsum = 0.f;
            #pragma unroll
            for (int ww = 0; ww < NWAVES; ++ww) rsum += part[par][ww][tid];

            // ---- LIF (exact reference expression order, no FMA) ----
            float xv  = xs[t];
            float pp  = xv * w_in;
            float q   = pp + rsum;
            float cur = q + bi;

            float aa = (-lv) / 20.0f;
            float bb = aa + cur;
            lv = lv + 0.042f * bb;
            float ls = (lv > 0.05f) ? 1.0f : 0.0f;
            lv = lv - ls * 0.05f;

            // ---- HRF oscillator ----
            float t1 = 35.0f * ls;
            float t2 = ga * hy;
            float t3 = ep * hz;
            float t4 = (t1 - t2) - t3;
            hz = hz + 0.042f * t4;
            hy = hy + 0.042f * hz;

            float sv = (hy - 0.05f) - ref;
            int sp = (sv > 0.0f) ? 1 : 0;
            ref = ref * ref_decay + (sp ? 1.0f : 0.0f);
            scount += sp;

            // ---- publish 4 self-validating tagged words (relaxed agent) ----
            if (t < NSTEP - 1) {
                unsigned long long bal = __ballot(sp);
                if ((tid & 31) == 0) {
                    unsigned int half = (tid & 32) ? (unsigned int)(bal >> 32)
                                                   : (unsigned int)bal;
                    unsigned long long payload =
                        (((unsigned long long)(t + 1)) << 32) | half;
                    __hip_atomic_store(
                        &masks[((size_t)par * NB + b) * MWORDS + (j << 2) + (tid >> 5)],
                        payload, __ATOMIC_RELAXED, __HIP_MEMORY_SCOPE_AGENT);
                }
            }
        }
    }

    if (tid < COLS)
        out[b * NHID + j * COLS + tid] = (float)scount * (1.0f / 512.0f);
}

extern "C" void kernel_launch(void* const* d_in, const int* in_sizes, int n_in,
                              void* d_out, int out_size, void* d_ws, size_t ws_size,
                              hipStream_t stream) {
    const float* x     = (const float*)d_in[0];
    const float* x2h   = (const float*)d_in[1];
    const float* h2h   = (const float*)d_in[2];
    const float* bias  = (const float*)d_in[3];
    const float* gamma = (const float*)d_in[4];
    const float* eps   = (const float*)d_in[5];
    float* out = (float*)d_out;

    // ws: [0,16384) u64 masks[2][NB][MWORDS]  (tag 0 => "not yet published")
    unsigned long long* masks = (unsigned long long*)d_ws;
    hipMemsetAsync(d_ws, 0, 16384, stream);

    float ref_decay = (float)exp(-(0.042 / 0.25));

    coesn_kernel<<<NB * NSPLIT, THREADS, 0, stream>>>(
        x, x2h, h2h, bias, gamma, eps, out, masks, ref_decay);
}